// Round 1
// baseline (1939.459 us; speedup 1.0000x reference)
//
#include <hip/hip_runtime.h>
#include <hip/hip_bf16.h>
#include <math.h>

// Problem constants (B,T,D,H) = (2,2048,1024,16), hd=64
#define B_  2
#define T_  2048
#define D_  1024
#define H_  16
#define HD_ 64

// ---------------------------------------------------------------------------
// Kernel A: qk projection GEMM
//   qk[m,n] = sum_k X[m,k]*W[n,k] + bias[n];  M=4096, N=2048, K=1024
//   scatter into q_ws / k_ws with (B,H,T,HD) layout
// ---------------------------------------------------------------------------
__global__ __launch_bounds__(256) void qk_gemm(const float* __restrict__ X,
                                               const float* __restrict__ W,
                                               const float* __restrict__ bias,
                                               float* __restrict__ qws,
                                               float* __restrict__ kws) {
    const int K = 1024;
    __shared__ float As[64][33];
    __shared__ float Bs[64][33];
    const int tid = threadIdx.x;
    const int tx = tid & 15, ty = tid >> 4;
    const int m0 = blockIdx.y * 64, n0 = blockIdx.x * 64;

    float acc[4][4] = {};

    for (int k0 = 0; k0 < K; k0 += 32) {
        // Stage 64x32 tiles of A and B (row-major, K contiguous), float4 loads.
        #pragma unroll
        for (int p = 0; p < 2; ++p) {
            int idx = tid + p * 256;         // 0..511 float4 slots
            int r   = idx >> 3;              // 64 rows
            int c   = (idx & 7) * 4;         // 32 k per row
            float4 av = *(const float4*)&X[(size_t)(m0 + r) * K + k0 + c];
            As[r][c + 0] = av.x; As[r][c + 1] = av.y;
            As[r][c + 2] = av.z; As[r][c + 3] = av.w;
            float4 bv = *(const float4*)&W[(size_t)(n0 + r) * K + k0 + c];
            Bs[r][c + 0] = bv.x; Bs[r][c + 1] = bv.y;
            Bs[r][c + 2] = bv.z; Bs[r][c + 3] = bv.w;
        }
        __syncthreads();
        #pragma unroll
        for (int kk = 0; kk < 32; ++kk) {
            float a[4], b[4];
            #pragma unroll
            for (int i = 0; i < 4; ++i) a[i] = As[ty * 4 + i][kk];
            #pragma unroll
            for (int j = 0; j < 4; ++j) b[j] = Bs[tx * 4 + j][kk];
            #pragma unroll
            for (int i = 0; i < 4; ++i)
                #pragma unroll
                for (int j = 0; j < 4; ++j) acc[i][j] += a[i] * b[j];
        }
        __syncthreads();
    }

    // Scatter with bias into (B,H,T,HD) q / k buffers.
    #pragma unroll
    for (int i = 0; i < 4; ++i) {
        int m = m0 + ty * 4 + i;
        int b = m >> 11, t = m & (T_ - 1);
        #pragma unroll
        for (int j = 0; j < 4; ++j) {
            int n = n0 + tx * 4 + j;
            float v = acc[i][j] + bias[n];
            if (n < D_) {
                int h = n >> 6, d = n & 63;
                qws[(((size_t)b * H_ + h) * T_ + t) * HD_ + d] = v;
            } else {
                int n2 = n - D_;
                int h = n2 >> 6, d = n2 & 63;
                kws[(((size_t)b * H_ + h) * T_ + t) * HD_ + d] = v;
            }
        }
    }
}

// ---------------------------------------------------------------------------
// Kernel B: v = einsum('btjd,ij->bitd', xt_heads, v_fact), out (B,H,T,HD)
// ---------------------------------------------------------------------------
__global__ __launch_bounds__(256) void head_mix_v(const float* __restrict__ xt,
                                                  const float* __restrict__ vf,
                                                  float* __restrict__ vws) {
    __shared__ float xl[1024];
    __shared__ float f[256];
    const int row = blockIdx.x;              // b*T + t
    const int b = row >> 11, t = row & (T_ - 1);
    const float* xr = xt + (size_t)row * D_;
    const int tid = threadIdx.x;
    #pragma unroll
    for (int i = tid; i < 1024; i += 256) xl[i] = xr[i];
    f[tid] = vf[tid];                        // H*H = 256
    __syncthreads();
    for (int o = tid; o < 1024; o += 256) {
        int i = o >> 6, d = o & 63;
        float acc = 0.f;
        #pragma unroll
        for (int j = 0; j < 16; ++j) acc += f[i * 16 + j] * xl[j * 64 + d];
        vws[(((size_t)b * H_ + i) * T_ + t) * HD_ + d] = acc;
    }
}

// ---------------------------------------------------------------------------
// Kernel C: causal ALiBi flash attention (fp32).
//   block = 256 threads = 4 waves; 16 query rows per block (4 per wave).
//   K/V tiles of 64 keys staged in LDS (pad 65 -> all hot reads <=2-way).
//   y written in (B,T,H,HD) layout.
// ---------------------------------------------------------------------------
__global__ __launch_bounds__(256) void attn(const float* __restrict__ qws,
                                            const float* __restrict__ kws,
                                            const float* __restrict__ vws,
                                            float* __restrict__ yws) {
    __shared__ float Kl[64][65];
    __shared__ float Vl[64][65];
    __shared__ float ql[16][64];

    const int tid  = threadIdx.x;
    const int lane = tid & 63, w = tid >> 6;
    const int bh = blockIdx.y;               // b*H + h
    const int b = bh >> 4, h = bh & 15;
    const int t0 = blockIdx.x * 16;
    const int tw = t0 + w * 4;               // this wave's first row
    const float slope = exp2f(-0.5f * (float)(h + 1));

    const float* qbase = qws + (size_t)bh * T_ * HD_;
    const float* kbase = kws + (size_t)bh * T_ * HD_;
    const float* vbase = vws + (size_t)bh * T_ * HD_;

    // load 16 q rows (256 float4)
    {
        int r = tid >> 4, c = (tid & 15) * 4;
        float4 qv = *(const float4*)&qbase[(size_t)(t0 + r) * HD_ + c];
        ql[r][c + 0] = qv.x; ql[r][c + 1] = qv.y;
        ql[r][c + 2] = qv.z; ql[r][c + 3] = qv.w;
    }

    float m[4] = {-INFINITY, -INFINITY, -INFINITY, -INFINITY};
    float l[4] = {0.f, 0.f, 0.f, 0.f};
    float o[4] = {0.f, 0.f, 0.f, 0.f};

    const int tmax = t0 + 15;
    for (int k0 = 0; k0 <= tmax; k0 += 64) {
        __syncthreads();
        // stage K,V tile: 1024 float4 each, 256 threads -> 4 passes
        #pragma unroll
        for (int p = 0; p < 4; ++p) {
            int idx = tid + p * 256;
            int r = idx >> 4, c = (idx & 15) * 4;
            float4 kv = *(const float4*)&kbase[(size_t)(k0 + r) * HD_ + c];
            Kl[r][c + 0] = kv.x; Kl[r][c + 1] = kv.y;
            Kl[r][c + 2] = kv.z; Kl[r][c + 3] = kv.w;
            float4 vv = *(const float4*)&vbase[(size_t)(k0 + r) * HD_ + c];
            Vl[r][c + 0] = vv.x; Vl[r][c + 1] = vv.y;
            Vl[r][c + 2] = vv.z; Vl[r][c + 3] = vv.w;
        }
        __syncthreads();

        if (k0 <= tw + 3) {                  // any of this wave's rows active
            float dot0 = 0.f, dot1 = 0.f, dot2 = 0.f, dot3 = 0.f;
            #pragma unroll
            for (int d = 0; d < 64; ++d) {
                float kv = Kl[lane][d];      // 2-way bank alias (free)
                dot0 += ql[w * 4 + 0][d] * kv;   // broadcast reads
                dot1 += ql[w * 4 + 1][d] * kv;
                dot2 += ql[w * 4 + 2][d] * kv;
                dot3 += ql[w * 4 + 3][d] * kv;
            }
            float dots[4] = {dot0, dot1, dot2, dot3};
            float p[4];
            const int kg = k0 + lane;
            #pragma unroll
            for (int r = 0; r < 4; ++r) {
                int tr = tw + r;
                float s = (kg <= tr)
                            ? 0.125f * dots[r] + slope * (float)(kg - tr)
                            : -INFINITY;
                float tm = s;
                #pragma unroll
                for (int off = 32; off > 0; off >>= 1)
                    tm = fmaxf(tm, __shfl_xor(tm, off));
                float mnew = fmaxf(m[r], tm);     // finite after first tile
                float corr = __expf(m[r] - mnew); // 0 when m=-inf
                p[r] = (kg <= tr) ? __expf(s - mnew) : 0.f;
                float ps = p[r];
                #pragma unroll
                for (int off = 32; off > 0; off >>= 1)
                    ps += __shfl_xor(ps, off);
                l[r] = l[r] * corr + ps;
                m[r] = mnew;
                o[r] *= corr;
            }
            #pragma unroll
            for (int j = 0; j < 64; ++j) {
                float vv = Vl[j][lane];      // 2-way bank alias (free)
                o[0] += __shfl(p[0], j) * vv;
                o[1] += __shfl(p[1], j) * vv;
                o[2] += __shfl(p[2], j) * vv;
                o[3] += __shfl(p[3], j) * vv;
            }
        }
    }

    // write y in (B,T,H,HD)
    #pragma unroll
    for (int r = 0; r < 4; ++r) {
        int t = tw + r;
        yws[(((size_t)b * T_ + t) * H_ + h) * HD_ + lane] = o[r] / l[r];
    }
}

// ---------------------------------------------------------------------------
// Kernel D: out = einsum('btjd,ij->btid', y, out_fact) -> (B,T,D) fp32
// ---------------------------------------------------------------------------
__global__ __launch_bounds__(256) void head_mix_out(const float* __restrict__ yws,
                                                    const float* __restrict__ of,
                                                    float* __restrict__ out) {
    __shared__ float yl[1024];
    __shared__ float f[256];
    const int row = blockIdx.x;              // b*T + t
    const float* yr = yws + (size_t)row * D_;
    const int tid = threadIdx.x;
    #pragma unroll
    for (int i = tid; i < 1024; i += 256) yl[i] = yr[i];
    f[tid] = of[tid];
    __syncthreads();
    for (int o = tid; o < 1024; o += 256) {
        int i = o >> 6, d = o & 63;
        float acc = 0.f;
        #pragma unroll
        for (int j = 0; j < 16; ++j) acc += f[i * 16 + j] * yl[j * 64 + d];
        out[(size_t)row * D_ + o] = acc;
    }
}

// ---------------------------------------------------------------------------
extern "C" void kernel_launch(void* const* d_in, const int* in_sizes, int n_in,
                              void* d_out, int out_size, void* d_ws, size_t ws_size,
                              hipStream_t stream) {
    const float* x_norm   = (const float*)d_in[0];
    const float* xt       = (const float*)d_in[1];
    const float* qk_w     = (const float*)d_in[2];
    const float* qk_b     = (const float*)d_in[3];
    const float* v_fact   = (const float*)d_in[4];
    const float* out_fact = (const float*)d_in[5];
    float* out = (float*)d_out;

    float* ws = (float*)d_ws;
    const size_t SZ = (size_t)B_ * H_ * T_ * HD_;   // 4M floats
    float* qws = ws;
    float* kws = ws + SZ;
    float* vws = ws + 2 * SZ;
    float* yws = ws + 3 * SZ;

    dim3 gA(2048 / 64, 4096 / 64);                  // (N tiles, M tiles)
    qk_gemm<<<gA, 256, 0, stream>>>(x_norm, qk_w, qk_b, qws, kws);
    head_mix_v<<<dim3(B_ * T_), 256, 0, stream>>>(xt, v_fact, vws);
    attn<<<dim3(T_ / 16, B_ * H_), 256, 0, stream>>>(qws, kws, vws, yws);
    head_mix_out<<<dim3(B_ * T_), 256, 0, stream>>>(yws, out_fact, out);
}

// Round 3
// 670.540 us; speedup vs baseline: 2.8924x; 2.8924x over previous
//
#include <hip/hip_runtime.h>
#include <hip/hip_bf16.h>
#include <math.h>

// Problem constants (B,T,D,H) = (2,2048,1024,16), hd=64
#define B_  2
#define T_  2048
#define D_  1024
#define H_  16
#define HD_ 64

typedef __attribute__((ext_vector_type(8))) short bf16x8;
typedef __attribute__((ext_vector_type(4))) float f32x4;

static __device__ __forceinline__ unsigned short f2bf(float f) {
    __hip_bfloat16 h = __float2bfloat16(f);
    return *reinterpret_cast<unsigned short*>(&h);
}

// ---------------------------------------------------------------------------
// Kernel A: qk projection GEMM (fp32 compute, known-good)
//   qk[m,n] = sum_k X[m,k]*W[n,k] + bias[n];  M=4096, N=2048, K=1024
//   emits bf16 q (pre-scaled by 1/8, exact) and bf16 k in (B,H,T,HD)
// ---------------------------------------------------------------------------
__global__ __launch_bounds__(256) void qk_gemm(const float* __restrict__ X,
                                               const float* __restrict__ W,
                                               const float* __restrict__ bias,
                                               __hip_bfloat16* __restrict__ qws,
                                               __hip_bfloat16* __restrict__ kws) {
    const int K = 1024;
    __shared__ float As[64][33];
    __shared__ float Bs[64][33];
    const int tid = threadIdx.x;
    const int tx = tid & 15, ty = tid >> 4;
    const int m0 = blockIdx.y * 64, n0 = blockIdx.x * 64;

    float acc[4][4] = {};

    for (int k0 = 0; k0 < K; k0 += 32) {
        #pragma unroll
        for (int p = 0; p < 2; ++p) {
            int idx = tid + p * 256;
            int r   = idx >> 3;
            int c   = (idx & 7) * 4;
            float4 av = *(const float4*)&X[(size_t)(m0 + r) * K + k0 + c];
            As[r][c + 0] = av.x; As[r][c + 1] = av.y;
            As[r][c + 2] = av.z; As[r][c + 3] = av.w;
            float4 bv = *(const float4*)&W[(size_t)(n0 + r) * K + k0 + c];
            Bs[r][c + 0] = bv.x; Bs[r][c + 1] = bv.y;
            Bs[r][c + 2] = bv.z; Bs[r][c + 3] = bv.w;
        }
        __syncthreads();
        #pragma unroll
        for (int kk = 0; kk < 32; ++kk) {
            float a[4], b[4];
            #pragma unroll
            for (int i = 0; i < 4; ++i) a[i] = As[ty * 4 + i][kk];
            #pragma unroll
            for (int j = 0; j < 4; ++j) b[j] = Bs[tx * 4 + j][kk];
            #pragma unroll
            for (int i = 0; i < 4; ++i)
                #pragma unroll
                for (int j = 0; j < 4; ++j) acc[i][j] += a[i] * b[j];
        }
        __syncthreads();
    }

    #pragma unroll
    for (int i = 0; i < 4; ++i) {
        int m = m0 + ty * 4 + i;
        int b = m >> 11, t = m & (T_ - 1);
        #pragma unroll
        for (int j = 0; j < 4; ++j) {
            int n = n0 + tx * 4 + j;
            float v = acc[i][j] + bias[n];
            if (n < D_) {
                int h = n >> 6, d = n & 63;
                qws[(((size_t)b * H_ + h) * T_ + t) * HD_ + d] =
                    __float2bfloat16(v * 0.125f);   // fold softmax scale (exact)
            } else {
                int n2 = n - D_;
                int h = n2 >> 6, d = n2 & 63;
                kws[(((size_t)b * H_ + h) * T_ + t) * HD_ + d] = __float2bfloat16(v);
            }
        }
    }
}

// ---------------------------------------------------------------------------
// Kernel B: v = einsum('btjd,ij->bitd'), emitted TRANSPOSED bf16 (B,H,HD,T)
//   block = (b, t-pair); packed 2xbf16 (t,t+1) stores -> 4B stores
// ---------------------------------------------------------------------------
__global__ __launch_bounds__(256) void head_mix_v(const float* __restrict__ xt,
                                                  const float* __restrict__ vf,
                                                  __hip_bfloat16* __restrict__ vt) {
    __shared__ float xl[2][1024];
    __shared__ float f[256];
    const int pair = blockIdx.x;             // 0..2047
    const int b = pair >> 10;
    const int t = (pair & 1023) * 2;
    const float* xr = xt + ((size_t)b * T_ + t) * D_;
    const int tid = threadIdx.x;
    #pragma unroll
    for (int i = tid; i < 1024; i += 256) {
        xl[0][i] = xr[i];
        xl[1][i] = xr[1024 + i];
    }
    f[tid] = vf[tid];
    __syncthreads();
    #pragma unroll
    for (int p = 0; p < 4; ++p) {
        int o = tid + p * 256;
        int i = o >> 6, d = o & 63;
        float a0 = 0.f, a1 = 0.f;
        #pragma unroll
        for (int j = 0; j < 16; ++j) {
            float fv = f[i * 16 + j];
            a0 += fv * xl[0][j * 64 + d];
            a1 += fv * xl[1][j * 64 + d];
        }
        unsigned pk = (unsigned)f2bf(a0) | ((unsigned)f2bf(a1) << 16);
        *(unsigned*)&vt[(((size_t)b * H_ + i) * HD_ + d) * T_ + t] = pk;
    }
}

// ---------------------------------------------------------------------------
// Kernel C: causal ALiBi flash attention, bf16 MFMA 16x16x32.
//   4 independent waves/block, 16 q-rows each. K/V fragments loaded directly
//   from global (L2-resident per head). P re-fragmented via per-wave LDS.
//   No __syncthreads anywhere.
// ---------------------------------------------------------------------------
__global__ __launch_bounds__(256) void attn_mfma(const __hip_bfloat16* __restrict__ qws,
                                                 const __hip_bfloat16* __restrict__ kws,
                                                 const __hip_bfloat16* __restrict__ vtws,
                                                 float* __restrict__ yws) {
    __shared__ float Pl[4][16][68];          // per-wave P tile (fp32)

    const int tid  = threadIdx.x;
    const int w    = tid >> 6;
    const int lane = tid & 63;
    const int l16  = lane & 15;
    const int g    = lane >> 4;

    // XCD-friendly mapping: 8 XCDs x 128 blocks; each XCD owns 4 heads.
    // Tile order reversed so long (high-t0) blocks launch first per head.
    const int bid    = blockIdx.x;           // 0..1023
    const int linear = (bid & 7) * 128 + (bid >> 3);
    const int bh     = linear >> 5;          // b*H + h
    const int tt     = 31 - (linear & 31);
    const int b = bh >> 4, h = bh & 15;
    const int t0  = tt * 64;
    const int tq0 = t0 + w * 16;             // this wave's first q row
    const float slope = exp2f(-0.5f * (float)(h + 1));

    const __hip_bfloat16* qb = qws  + (size_t)bh * (T_ * HD_);
    const __hip_bfloat16* kb = kws  + (size_t)bh * (T_ * HD_);
    const __hip_bfloat16* vb = vtws + (size_t)bh * (HD_ * T_);

    // Q fragments: A[m=q][k=d]; lane reads Q[tq0+l16][32*ks + 8*g .. +7]
    bf16x8 aq[2];
    #pragma unroll
    for (int ks = 0; ks < 2; ++ks)
        aq[ks] = *(const bf16x8*)(qb + (size_t)(tq0 + l16) * HD_ + ks * 32 + g * 8);

    f32x4 oacc[4] = {};                      // df -> Y[q=4g+r][d=16df+l16]
    float m_[4] = {-INFINITY, -INFINITY, -INFINITY, -INFINITY};
    float l_[4] = {0.f, 0.f, 0.f, 0.f};

    const int q_hi = tq0 + 15;
    for (int k0 = 0; k0 <= q_hi; k0 += 64) {
        // K fragments: B[k=d][n=key]; lane reads K[k0+16nf+l16][32ks+8g..+7]
        bf16x8 bk[4][2];
        #pragma unroll
        for (int nf = 0; nf < 4; ++nf)
            #pragma unroll
            for (int ks = 0; ks < 2; ++ks)
                bk[nf][ks] = *(const bf16x8*)(kb + (size_t)(k0 + nf * 16 + l16) * HD_ + ks * 32 + g * 8);
        // V fragments: B[k=key][n=d]; lane reads Vt[16df+l16][k0+32ks+8g..+7]
        bf16x8 bv[4][2];
        #pragma unroll
        for (int df = 0; df < 4; ++df)
            #pragma unroll
            for (int ks = 0; ks < 2; ++ks)
                bv[df][ks] = *(const bf16x8*)(vb + (size_t)(df * 16 + l16) * T_ + k0 + ks * 32 + g * 8);

        // S = Q.K^T : acc frag nf -> S[q=4g+r][key=k0+16nf+l16]
        f32x4 s[4] = {};
        #pragma unroll
        for (int nf = 0; nf < 4; ++nf)
            #pragma unroll
            for (int ks = 0; ks < 2; ++ks)
                s[nf] = __builtin_amdgcn_mfma_f32_16x16x32_bf16(aq[ks], bk[nf][ks], s[nf], 0, 0, 0);

        // online softmax (per r = 4 q-rows/lane; reduce across l16 via shfl_xor)
        #pragma unroll
        for (int r = 0; r < 4; ++r) {
            const int tq = tq0 + g * 4 + r;
            float sv[4], mx = -INFINITY;
            #pragma unroll
            for (int nf = 0; nf < 4; ++nf) {
                int kg = k0 + nf * 16 + l16;
                float x = s[nf][r] + slope * (float)(kg - tq);
                sv[nf] = (kg <= tq) ? x : -INFINITY;
                mx = fmaxf(mx, sv[nf]);
            }
            #pragma unroll
            for (int off = 8; off >= 1; off >>= 1)
                mx = fmaxf(mx, __shfl_xor(mx, off));
            float mnew = fmaxf(m_[r], mx);
            float corr = __expf(m_[r] - mnew);   // 0 on first tile
            float ps = 0.f;
            float pv[4];
            #pragma unroll
            for (int nf = 0; nf < 4; ++nf) {
                pv[nf] = __expf(sv[nf] - mnew);  // exp(-inf)=0 for masked
                ps += pv[nf];
            }
            #pragma unroll
            for (int off = 8; off >= 1; off >>= 1)
                ps += __shfl_xor(ps, off);
            l_[r] = l_[r] * corr + ps;
            m_[r] = mnew;
            #pragma unroll
            for (int df = 0; df < 4; ++df)
                oacc[df][r] *= corr;
            #pragma unroll
            for (int nf = 0; nf < 4; ++nf)
                Pl[w][g * 4 + r][l16 + nf * 16] = pv[nf];
        }

        // re-fragment P: A[m=q][k=key]; lane reads Pl[w][l16][32ks+8g..+7]
        bf16x8 ap[2];
        #pragma unroll
        for (int ks = 0; ks < 2; ++ks) {
            const float* pr = &Pl[w][l16][ks * 32 + g * 8];
            bf16x8 tmp;
            #pragma unroll
            for (int j = 0; j < 8; ++j)
                tmp[j] = (short)f2bf(pr[j]);
            ap[ks] = tmp;
        }

        // Y += P.V
        #pragma unroll
        for (int df = 0; df < 4; ++df)
            #pragma unroll
            for (int ks = 0; ks < 2; ++ks)
                oacc[df] = __builtin_amdgcn_mfma_f32_16x16x32_bf16(ap[ks], bv[df][ks], oacc[df], 0, 0, 0);
    }

    // epilogue: y (B,T,H,HD) fp32
    #pragma unroll
    for (int df = 0; df < 4; ++df)
        #pragma unroll
        for (int r = 0; r < 4; ++r) {
            int tq = tq0 + g * 4 + r;
            yws[(((size_t)b * T_ + tq) * H_ + h) * HD_ + df * 16 + l16] =
                oacc[df][r] / l_[r];
        }
}

// ---------------------------------------------------------------------------
// Kernel D: out = einsum('btjd,ij->btid', y, out_fact) -> (B,T,D) fp32
// ---------------------------------------------------------------------------
__global__ __launch_bounds__(256) void head_mix_out(const float* __restrict__ yws,
                                                    const float* __restrict__ of,
                                                    float* __restrict__ out) {
    __shared__ float yl[1024];
    __shared__ float f[256];
    const int row = blockIdx.x;
    const float* yr = yws + (size_t)row * D_;
    const int tid = threadIdx.x;
    #pragma unroll
    for (int i = tid; i < 1024; i += 256) yl[i] = yr[i];
    f[tid] = of[tid];
    __syncthreads();
    for (int o = tid; o < 1024; o += 256) {
        int i = o >> 6, d = o & 63;
        float acc = 0.f;
        #pragma unroll
        for (int j = 0; j < 16; ++j) acc += f[i * 16 + j] * yl[j * 64 + d];
        out[(size_t)row * D_ + o] = acc;
    }
}

// ---------------------------------------------------------------------------
extern "C" void kernel_launch(void* const* d_in, const int* in_sizes, int n_in,
                              void* d_out, int out_size, void* d_ws, size_t ws_size,
                              hipStream_t stream) {
    const float* x_norm   = (const float*)d_in[0];
    const float* xt       = (const float*)d_in[1];
    const float* qk_w     = (const float*)d_in[2];
    const float* qk_b     = (const float*)d_in[3];
    const float* v_fact   = (const float*)d_in[4];
    const float* out_fact = (const float*)d_in[5];
    float* out = (float*)d_out;

    const size_t SZ = (size_t)B_ * H_ * T_ * HD_;        // 4M elements
    __hip_bfloat16* qws = (__hip_bfloat16*)d_ws;
    __hip_bfloat16* kws = qws + SZ;
    __hip_bfloat16* vt  = kws + SZ;
    float*          yws = (float*)(vt + SZ);

    dim3 gA(2048 / 64, 4096 / 64);
    qk_gemm<<<gA, 256, 0, stream>>>(x_norm, qk_w, qk_b, qws, kws);
    head_mix_v<<<dim3(B_ * T_ / 2), 256, 0, stream>>>(xt, v_fact, vt);
    attn_mfma<<<dim3(1024), 256, 0, stream>>>(qws, kws, vt, yws);
    head_mix_out<<<dim3(B_ * T_), 256, 0, stream>>>(yws, out_fact, out);
}

// Round 6
// 369.833 us; speedup vs baseline: 5.2441x; 1.8131x over previous
//
#include <hip/hip_runtime.h>
#include <hip/hip_bf16.h>
#include <math.h>

// Problem constants (B,T,D,H) = (2,2048,1024,16), hd=64
#define B_  2
#define T_  2048
#define D_  1024
#define H_  16
#define HD_ 64

typedef __attribute__((ext_vector_type(8))) short bf16x8;
typedef __attribute__((ext_vector_type(4))) float f32x4;

#define GAS __attribute__((address_space(1)))
#define LAS __attribute__((address_space(3)))

static __device__ __forceinline__ unsigned short f2bf(float f) {
    __hip_bfloat16 h = __float2bfloat16(f);
    return *reinterpret_cast<unsigned short*>(&h);
}

// ---------------------------------------------------------------------------
// Kernel 0: fp32 -> bf16 cast, 8 elements/thread, 16B stores
// ---------------------------------------------------------------------------
__global__ __launch_bounds__(256) void cast_bf16(const float* __restrict__ in,
                                                 __hip_bfloat16* __restrict__ out,
                                                 int n8) {
    int i = blockIdx.x * 256 + threadIdx.x;
    if (i >= n8) return;
    float4 a = ((const float4*)in)[(size_t)i * 2];
    float4 b = ((const float4*)in)[(size_t)i * 2 + 1];
    union { unsigned short u[8]; bf16x8 v; } r;
    r.u[0] = f2bf(a.x); r.u[1] = f2bf(a.y); r.u[2] = f2bf(a.z); r.u[3] = f2bf(a.w);
    r.u[4] = f2bf(b.x); r.u[5] = f2bf(b.y); r.u[6] = f2bf(b.z); r.u[7] = f2bf(b.w);
    *(bf16x8*)(out + (size_t)i * 8) = r.v;
}

// ---------------------------------------------------------------------------
// Kernel A: qk projection GEMM, bf16 MFMA (m97 structure).
//   C[m,n] = sum_k Xb[m,k]*Wb[n,k] + bias[n];  M=4096, N=2048, K=1024
//   128x128 tile, BK=32, 4 waves (2x2, 64x64 each), global_load_lds staging.
//   Epilogue: bias, q-scale 1/8, bf16 scatter to (B,H,T,HD) q / k.
// ---------------------------------------------------------------------------
__global__ __launch_bounds__(256) void qk_gemm_mfma(const __hip_bfloat16* __restrict__ Xb,
                                                    const __hip_bfloat16* __restrict__ Wb,
                                                    const float* __restrict__ bias,
                                                    __hip_bfloat16* __restrict__ qws,
                                                    __hip_bfloat16* __restrict__ kws) {
    __shared__ __hip_bfloat16 As[128 * 32];   // linear row-major [128][32], 8 KB
    __shared__ __hip_bfloat16 Bs[128 * 32];

    const int tid  = threadIdx.x;
    const int w    = tid >> 6, lane = tid & 63;
    const int l16  = lane & 15, g = lane >> 4;
    const int wr   = w >> 1, wc = w & 1;
    const int m0   = blockIdx.y * 128, n0 = blockIdx.x * 128;
    const int K    = D_;

    // staging decomposition: 8 segments of 1024B per tile; wave w does s=w, s=w+4.
    // lane l -> LDS bytes s*1024 + l*16  => row s*16 + (l>>2), k-col (l&3)*8
    const int sr = lane >> 2;
    const int sk = (lane & 3) * 8;

    f32x4 acc[4][4] = {};

    for (int k0 = 0; k0 < K; k0 += 32) {
        __syncthreads();
        #pragma unroll
        for (int p = 0; p < 2; ++p) {
            int s = w + p * 4;
            int r = s * 16 + sr;
            __builtin_amdgcn_global_load_lds(
                (const GAS void*)(const void*)(Xb + (size_t)(m0 + r) * K + k0 + sk),
                (LAS void*)(void*)((char*)As + s * 1024), 16, 0, 0);
            __builtin_amdgcn_global_load_lds(
                (const GAS void*)(const void*)(Wb + (size_t)(n0 + r) * K + k0 + sk),
                (LAS void*)(void*)((char*)Bs + s * 1024), 16, 0, 0);
        }
        __syncthreads();   // compiler drains vmcnt before barrier

        bf16x8 af[4], bfr[4];
        #pragma unroll
        for (int mi = 0; mi < 4; ++mi)
            af[mi] = *(const bf16x8*)(As + (wr * 64 + mi * 16 + l16) * 32 + g * 8);
        #pragma unroll
        for (int ni = 0; ni < 4; ++ni)
            bfr[ni] = *(const bf16x8*)(Bs + (wc * 64 + ni * 16 + l16) * 32 + g * 8);
        #pragma unroll
        for (int mi = 0; mi < 4; ++mi)
            #pragma unroll
            for (int ni = 0; ni < 4; ++ni)
                acc[mi][ni] = __builtin_amdgcn_mfma_f32_16x16x32_bf16(
                                  af[mi], bfr[ni], acc[mi][ni], 0, 0, 0);
    }

    // Epilogue. n-side of a block is uniformly q (n0<1024) or k (n0>=1024).
    #pragma unroll
    for (int ni = 0; ni < 4; ++ni) {
        int n = n0 + wc * 64 + ni * 16 + l16;
        float bv = bias[n];
        bool isq = (n < D_);
        int nn = isq ? n : n - D_;
        int h = nn >> 6, d = nn & 63;
        float scale = isq ? 0.125f : 1.0f;
        __hip_bfloat16* dst = isq ? qws : kws;
        #pragma unroll
        for (int mi = 0; mi < 4; ++mi) {
            #pragma unroll
            for (int j = 0; j < 4; ++j) {
                int m = m0 + wr * 64 + mi * 16 + g * 4 + j;
                int b = m >> 11, t = m & (T_ - 1);
                dst[(((size_t)b * H_ + h) * T_ + t) * HD_ + d] =
                    __float2bfloat16((acc[mi][ni][j] + bv) * scale);
            }
        }
    }
}

// ---------------------------------------------------------------------------
// Kernel B: v = einsum('btjd,ij->bitd'), emitted TRANSPOSED bf16 (B,H,HD,T)
// ---------------------------------------------------------------------------
__global__ __launch_bounds__(256) void head_mix_v(const float* __restrict__ xt,
                                                  const float* __restrict__ vf,
                                                  __hip_bfloat16* __restrict__ vt) {
    __shared__ float xl[2][1024];
    __shared__ float f[256];
    const int pair = blockIdx.x;             // 0..2047
    const int b = pair >> 10;
    const int t = (pair & 1023) * 2;
    const float* xr = xt + ((size_t)b * T_ + t) * D_;
    const int tid = threadIdx.x;
    #pragma unroll
    for (int i = tid; i < 1024; i += 256) {
        xl[0][i] = xr[i];
        xl[1][i] = xr[1024 + i];
    }
    f[tid] = vf[tid];
    __syncthreads();
    #pragma unroll
    for (int p = 0; p < 4; ++p) {
        int o = tid + p * 256;
        int i = o >> 6, d = o & 63;
        float a0 = 0.f, a1 = 0.f;
        #pragma unroll
        for (int j = 0; j < 16; ++j) {
            float fv = f[i * 16 + j];
            a0 += fv * xl[0][j * 64 + d];
            a1 += fv * xl[1][j * 64 + d];
        }
        unsigned pk = (unsigned)f2bf(a0) | ((unsigned)f2bf(a1) << 16);
        *(unsigned*)&vt[(((size_t)b * H_ + i) * HD_ + d) * T_ + t] = pk;
    }
}

// ---------------------------------------------------------------------------
// Kernel C: causal ALiBi flash attention, bf16 MFMA 16x16x32 (unchanged).
// ---------------------------------------------------------------------------
__global__ __launch_bounds__(256) void attn_mfma(const __hip_bfloat16* __restrict__ qws,
                                                 const __hip_bfloat16* __restrict__ kws,
                                                 const __hip_bfloat16* __restrict__ vtws,
                                                 float* __restrict__ yws) {
    __shared__ float Pl[4][16][68];          // per-wave P tile (fp32)

    const int tid  = threadIdx.x;
    const int w    = tid >> 6;
    const int lane = tid & 63;
    const int l16  = lane & 15;
    const int g    = lane >> 4;

    const int bid    = blockIdx.x;           // 0..1023
    const int linear = (bid & 7) * 128 + (bid >> 3);
    const int bh     = linear >> 5;          // b*H + h
    const int tt     = 31 - (linear & 31);
    const int b = bh >> 4, h = bh & 15;
    const int t0  = tt * 64;
    const int tq0 = t0 + w * 16;
    const float slope = exp2f(-0.5f * (float)(h + 1));

    const __hip_bfloat16* qb = qws  + (size_t)bh * (T_ * HD_);
    const __hip_bfloat16* kb = kws  + (size_t)bh * (T_ * HD_);
    const __hip_bfloat16* vb = vtws + (size_t)bh * (HD_ * T_);

    bf16x8 aq[2];
    #pragma unroll
    for (int ks = 0; ks < 2; ++ks)
        aq[ks] = *(const bf16x8*)(qb + (size_t)(tq0 + l16) * HD_ + ks * 32 + g * 8);

    f32x4 oacc[4] = {};
    float m_[4] = {-INFINITY, -INFINITY, -INFINITY, -INFINITY};
    float l_[4] = {0.f, 0.f, 0.f, 0.f};

    const int q_hi = tq0 + 15;
    for (int k0 = 0; k0 <= q_hi; k0 += 64) {
        bf16x8 bk[4][2];
        #pragma unroll
        for (int nf = 0; nf < 4; ++nf)
            #pragma unroll
            for (int ks = 0; ks < 2; ++ks)
                bk[nf][ks] = *(const bf16x8*)(kb + (size_t)(k0 + nf * 16 + l16) * HD_ + ks * 32 + g * 8);
        bf16x8 bv[4][2];
        #pragma unroll
        for (int df = 0; df < 4; ++df)
            #pragma unroll
            for (int ks = 0; ks < 2; ++ks)
                bv[df][ks] = *(const bf16x8*)(vb + (size_t)(df * 16 + l16) * T_ + k0 + ks * 32 + g * 8);

        f32x4 s[4] = {};
        #pragma unroll
        for (int nf = 0; nf < 4; ++nf)
            #pragma unroll
            for (int ks = 0; ks < 2; ++ks)
                s[nf] = __builtin_amdgcn_mfma_f32_16x16x32_bf16(aq[ks], bk[nf][ks], s[nf], 0, 0, 0);

        #pragma unroll
        for (int r = 0; r < 4; ++r) {
            const int tq = tq0 + g * 4 + r;
            float sv[4], mx = -INFINITY;
            #pragma unroll
            for (int nf = 0; nf < 4; ++nf) {
                int kg = k0 + nf * 16 + l16;
                float x = s[nf][r] + slope * (float)(kg - tq);
                sv[nf] = (kg <= tq) ? x : -INFINITY;
                mx = fmaxf(mx, sv[nf]);
            }
            #pragma unroll
            for (int off = 8; off >= 1; off >>= 1)
                mx = fmaxf(mx, __shfl_xor(mx, off));
            float mnew = fmaxf(m_[r], mx);
            float corr = __expf(m_[r] - mnew);
            float ps = 0.f;
            float pv[4];
            #pragma unroll
            for (int nf = 0; nf < 4; ++nf) {
                pv[nf] = __expf(sv[nf] - mnew);
                ps += pv[nf];
            }
            #pragma unroll
            for (int off = 8; off >= 1; off >>= 1)
                ps += __shfl_xor(ps, off);
            l_[r] = l_[r] * corr + ps;
            m_[r] = mnew;
            #pragma unroll
            for (int df = 0; df < 4; ++df)
                oacc[df][r] *= corr;
            #pragma unroll
            for (int nf = 0; nf < 4; ++nf)
                Pl[w][g * 4 + r][l16 + nf * 16] = pv[nf];
        }

        bf16x8 ap[2];
        #pragma unroll
        for (int ks = 0; ks < 2; ++ks) {
            const float* pr = &Pl[w][l16][ks * 32 + g * 8];
            bf16x8 tmp;
            #pragma unroll
            for (int j = 0; j < 8; ++j)
                tmp[j] = (short)f2bf(pr[j]);
            ap[ks] = tmp;
        }

        #pragma unroll
        for (int df = 0; df < 4; ++df)
            #pragma unroll
            for (int ks = 0; ks < 2; ++ks)
                oacc[df] = __builtin_amdgcn_mfma_f32_16x16x32_bf16(ap[ks], bv[df][ks], oacc[df], 0, 0, 0);
    }

    #pragma unroll
    for (int df = 0; df < 4; ++df)
        #pragma unroll
        for (int r = 0; r < 4; ++r) {
            int tq = tq0 + g * 4 + r;
            yws[(((size_t)b * T_ + tq) * H_ + h) * HD_ + df * 16 + l16] =
                oacc[df][r] / l_[r];
        }
}

// ---------------------------------------------------------------------------
// Kernel D: out = einsum('btjd,ij->btid', y, out_fact) -> (B,T,D) fp32
// ---------------------------------------------------------------------------
__global__ __launch_bounds__(256) void head_mix_out(const float* __restrict__ yws,
                                                    const float* __restrict__ of,
                                                    float* __restrict__ out) {
    __shared__ float yl[1024];
    __shared__ float f[256];
    const int row = blockIdx.x;
    const float* yr = yws + (size_t)row * D_;
    const int tid = threadIdx.x;
    #pragma unroll
    for (int i = tid; i < 1024; i += 256) yl[i] = yr[i];
    f[tid] = of[tid];
    __syncthreads();
    for (int o = tid; o < 1024; o += 256) {
        int i = o >> 6, d = o & 63;
        float acc = 0.f;
        #pragma unroll
        for (int j = 0; j < 16; ++j) acc += f[i * 16 + j] * yl[j * 64 + d];
        out[(size_t)row * D_ + o] = acc;
    }
}

// ---------------------------------------------------------------------------
extern "C" void kernel_launch(void* const* d_in, const int* in_sizes, int n_in,
                              void* d_out, int out_size, void* d_ws, size_t ws_size,
                              hipStream_t stream) {
    const float* x_norm   = (const float*)d_in[0];
    const float* xt       = (const float*)d_in[1];
    const float* qk_w     = (const float*)d_in[2];
    const float* qk_b     = (const float*)d_in[3];
    const float* v_fact   = (const float*)d_in[4];
    const float* out_fact = (const float*)d_in[5];
    float* out = (float*)d_out;

    const size_t SZ = (size_t)B_ * H_ * T_ * HD_;        // 4M elements
    __hip_bfloat16* qws = (__hip_bfloat16*)d_ws;         // 8 MB
    __hip_bfloat16* kws = qws + SZ;                      // 8 MB
    __hip_bfloat16* vt  = kws + SZ;                      // 8 MB
    float*          yws = (float*)(vt + SZ);             // 16 MB
    __hip_bfloat16* Xb  = (__hip_bfloat16*)(yws + SZ);   // 8 MB
    __hip_bfloat16* Wb  = Xb + SZ;                       // 4 MB

    cast_bf16<<<dim3(2048), 256, 0, stream>>>(x_norm, Xb, 4 * 1024 * 1024 / 8);
    cast_bf16<<<dim3(1024), 256, 0, stream>>>(qk_w, Wb, 2 * 1024 * 1024 / 8);

    qk_gemm_mfma<<<dim3(2048 / 128, 4096 / 128), 256, 0, stream>>>(Xb, Wb, qk_b, qws, kws);
    head_mix_v<<<dim3(B_ * T_ / 2), 256, 0, stream>>>(xt, v_fact, vt);
    attn_mfma<<<dim3(1024), 256, 0, stream>>>(qws, kws, vt, yws);
    head_mix_out<<<dim3(B_ * T_), 256, 0, stream>>>(yws, out_fact, out);
}

// Round 7
// 262.637 us; speedup vs baseline: 7.3846x; 1.4082x over previous
//
#include <hip/hip_runtime.h>
#include <hip/hip_bf16.h>
#include <math.h>

// Problem constants (B,T,D,H) = (2,2048,1024,16), hd=64
#define B_  2
#define T_  2048
#define D_  1024
#define H_  16
#define HD_ 64

typedef __attribute__((ext_vector_type(8))) short bf16x8;
typedef __attribute__((ext_vector_type(4))) float f32x4;

#define GAS __attribute__((address_space(1)))
#define LAS __attribute__((address_space(3)))

static __device__ __forceinline__ unsigned short f2bf(float f) {
    __hip_bfloat16 h = __float2bfloat16(f);
    return *reinterpret_cast<unsigned short*>(&h);
}

// ---------------------------------------------------------------------------
// Kernel 0: fp32 -> bf16 cast, 8 elements/thread, 16B stores
// ---------------------------------------------------------------------------
__global__ __launch_bounds__(256) void cast_bf16(const float* __restrict__ in,
                                                 __hip_bfloat16* __restrict__ out,
                                                 int n8) {
    int i = blockIdx.x * 256 + threadIdx.x;
    if (i >= n8) return;
    float4 a = ((const float4*)in)[(size_t)i * 2];
    float4 b = ((const float4*)in)[(size_t)i * 2 + 1];
    union { unsigned short u[8]; bf16x8 v; } r;
    r.u[0] = f2bf(a.x); r.u[1] = f2bf(a.y); r.u[2] = f2bf(a.z); r.u[3] = f2bf(a.w);
    r.u[4] = f2bf(b.x); r.u[5] = f2bf(b.y); r.u[6] = f2bf(b.z); r.u[7] = f2bf(b.w);
    *(bf16x8*)(out + (size_t)i * 8) = r.v;
}

// ---------------------------------------------------------------------------
// Kernel A: qk projection GEMM, bf16 MFMA (m97 structure). Unchanged.
// ---------------------------------------------------------------------------
__global__ __launch_bounds__(256) void qk_gemm_mfma(const __hip_bfloat16* __restrict__ Xb,
                                                    const __hip_bfloat16* __restrict__ Wb,
                                                    const float* __restrict__ bias,
                                                    __hip_bfloat16* __restrict__ qws,
                                                    __hip_bfloat16* __restrict__ kws) {
    __shared__ __hip_bfloat16 As[128 * 32];   // linear row-major [128][32], 8 KB
    __shared__ __hip_bfloat16 Bs[128 * 32];

    const int tid  = threadIdx.x;
    const int w    = tid >> 6, lane = tid & 63;
    const int l16  = lane & 15, g = lane >> 4;
    const int wr   = w >> 1, wc = w & 1;
    const int m0   = blockIdx.y * 128, n0 = blockIdx.x * 128;
    const int K    = D_;

    const int sr = lane >> 2;
    const int sk = (lane & 3) * 8;

    f32x4 acc[4][4] = {};

    for (int k0 = 0; k0 < K; k0 += 32) {
        __syncthreads();
        #pragma unroll
        for (int p = 0; p < 2; ++p) {
            int s = w + p * 4;
            int r = s * 16 + sr;
            __builtin_amdgcn_global_load_lds(
                (const GAS void*)(const void*)(Xb + (size_t)(m0 + r) * K + k0 + sk),
                (LAS void*)(void*)((char*)As + s * 1024), 16, 0, 0);
            __builtin_amdgcn_global_load_lds(
                (const GAS void*)(const void*)(Wb + (size_t)(n0 + r) * K + k0 + sk),
                (LAS void*)(void*)((char*)Bs + s * 1024), 16, 0, 0);
        }
        __syncthreads();

        bf16x8 af[4], bfr[4];
        #pragma unroll
        for (int mi = 0; mi < 4; ++mi)
            af[mi] = *(const bf16x8*)(As + (wr * 64 + mi * 16 + l16) * 32 + g * 8);
        #pragma unroll
        for (int ni = 0; ni < 4; ++ni)
            bfr[ni] = *(const bf16x8*)(Bs + (wc * 64 + ni * 16 + l16) * 32 + g * 8);
        #pragma unroll
        for (int mi = 0; mi < 4; ++mi)
            #pragma unroll
            for (int ni = 0; ni < 4; ++ni)
                acc[mi][ni] = __builtin_amdgcn_mfma_f32_16x16x32_bf16(
                                  af[mi], bfr[ni], acc[mi][ni], 0, 0, 0);
    }

    #pragma unroll
    for (int ni = 0; ni < 4; ++ni) {
        int n = n0 + wc * 64 + ni * 16 + l16;
        float bv = bias[n];
        bool isq = (n < D_);
        int nn = isq ? n : n - D_;
        int h = nn >> 6, d = nn & 63;
        float scale = isq ? 0.125f : 1.0f;
        __hip_bfloat16* dst = isq ? qws : kws;
        #pragma unroll
        for (int mi = 0; mi < 4; ++mi) {
            #pragma unroll
            for (int j = 0; j < 4; ++j) {
                int m = m0 + wr * 64 + mi * 16 + g * 4 + j;
                int b = m >> 11, t = m & (T_ - 1);
                dst[(((size_t)b * H_ + h) * T_ + t) * HD_ + d] =
                    __float2bfloat16((acc[mi][ni][j] + bv) * scale);
            }
        }
    }
}

// ---------------------------------------------------------------------------
// Kernel B: v = einsum('btjd,ij->bitd'), emitted TRANSPOSED bf16 (B,H,HD,T)
// ---------------------------------------------------------------------------
__global__ __launch_bounds__(256) void head_mix_v(const float* __restrict__ xt,
                                                  const float* __restrict__ vf,
                                                  __hip_bfloat16* __restrict__ vt) {
    __shared__ float xl[2][1024];
    __shared__ float f[256];
    const int pair = blockIdx.x;             // 0..2047
    const int b = pair >> 10;
    const int t = (pair & 1023) * 2;
    const float* xr = xt + ((size_t)b * T_ + t) * D_;
    const int tid = threadIdx.x;
    #pragma unroll
    for (int i = tid; i < 1024; i += 256) {
        xl[0][i] = xr[i];
        xl[1][i] = xr[1024 + i];
    }
    f[tid] = vf[tid];
    __syncthreads();
    #pragma unroll
    for (int p = 0; p < 4; ++p) {
        int o = tid + p * 256;
        int i = o >> 6, d = o & 63;
        float a0 = 0.f, a1 = 0.f;
        #pragma unroll
        for (int j = 0; j < 16; ++j) {
            float fv = f[i * 16 + j];
            a0 += fv * xl[0][j * 64 + d];
            a1 += fv * xl[1][j * 64 + d];
        }
        unsigned pk = (unsigned)f2bf(a0) | ((unsigned)f2bf(a1) << 16);
        *(unsigned*)&vt[(((size_t)b * H_ + i) * HD_ + d) * T_ + t] = pk;
    }
}

// ---------------------------------------------------------------------------
// Kernel C: causal ALiBi flash attention, bf16 MFMA 16x16x32.
//   1 wave per block (64 thr). Wave handles q-row-tiles j and 127-j
//   (uniform ~33 KV-tiles per wave). Swapped QK^T (S^T = mfma(K,Q)) makes
//   the key-reduction 2 shuffle hops; P^T round-trips LDS via b128 ops.
//   K fragments register-double-buffered (prefetch next tile).
// ---------------------------------------------------------------------------
__global__ __launch_bounds__(64) void attn_mfma(const __hip_bfloat16* __restrict__ qws,
                                                const __hip_bfloat16* __restrict__ kws,
                                                const __hip_bfloat16* __restrict__ vtws,
                                                float* __restrict__ yws) {
    __shared__ float Pl[16][68];             // P^T tile: [q][key], 4.25 KB

    const int lane = threadIdx.x;            // 0..63
    const int l16  = lane & 15;
    const int g    = lane >> 4;

    // XCD swizzle: 8 XCDs x 256 blocks; each XCD owns 4 heads (KV fits L2).
    const int bid    = blockIdx.x;           // 0..2047
    const int linear = (bid & 7) * 256 + (bid >> 3);
    const int bh     = linear >> 6;          // b*H + h
    const int pj     = linear & 63;          // pair index
    const int b = bh >> 4, h = bh & 15;
    const float slope = exp2f(-0.5f * (float)(h + 1));

    const __hip_bfloat16* qb = qws  + (size_t)bh * (T_ * HD_);
    const __hip_bfloat16* kb = kws  + (size_t)bh * (T_ * HD_);
    const __hip_bfloat16* vb = vtws + (size_t)bh * (HD_ * T_);

    #pragma unroll
    for (int part = 0; part < 2; ++part) {
        const int j    = part ? 127 - pj : pj;   // q-row-tile (16 rows)
        const int tq0  = j * 16;
        const int q_hi = tq0 + 15;
        const int tq   = tq0 + l16;              // this lane's softmax row

        // Q fragments (B-operand of S^T, A-operand shape for PV's P):
        bf16x8 aq[2];
        #pragma unroll
        for (int ks = 0; ks < 2; ++ks)
            aq[ks] = *(const bf16x8*)(qb + (size_t)(tq0 + l16) * HD_ + ks * 32 + g * 8);

        f32x4 oacc[4] = {};                  // df -> Y[q=g*4+r][d=16df+l16]
        float m_s = -INFINITY, l_s = 0.f;

        bf16x8 kA[4][2], kB[4][2];

        auto loadK = [&](bf16x8 (&dst)[4][2], int k0) {
            #pragma unroll
            for (int kf = 0; kf < 4; ++kf)
                #pragma unroll
                for (int ks = 0; ks < 2; ++ks)
                    dst[kf][ks] = *(const bf16x8*)(kb + (size_t)(k0 + kf * 16 + l16) * HD_ + ks * 32 + g * 8);
        };

        auto tile = [&](const bf16x8 (&bk)[4][2], int k0) {
            // V fragments for this tile (latency hidden under QK + softmax)
            bf16x8 bv[4][2];
            #pragma unroll
            for (int df = 0; df < 4; ++df)
                #pragma unroll
                for (int ks = 0; ks < 2; ++ks)
                    bv[df][ks] = *(const bf16x8*)(vb + (size_t)(df * 16 + l16) * T_ + k0 + ks * 32 + g * 8);

            // S^T = K.Q : frag kf -> S^T[key=k0+kf*16+g*4+r][q=tq0+l16]
            f32x4 s[4] = {};
            #pragma unroll
            for (int kf = 0; kf < 4; ++kf)
                #pragma unroll
                for (int ks = 0; ks < 2; ++ks)
                    s[kf] = __builtin_amdgcn_mfma_f32_16x16x32_bf16(bk[kf][ks], aq[ks], s[kf], 0, 0, 0);

            // bias + mask; lane-local max over its 16 keys, 2-hop reduce
            float pvv[4][4];
            float mx = -INFINITY;
            #pragma unroll
            for (int kf = 0; kf < 4; ++kf)
                #pragma unroll
                for (int r = 0; r < 4; ++r) {
                    int kg = k0 + kf * 16 + g * 4 + r;
                    float x = s[kf][r] + slope * (float)(kg - tq);
                    x = (kg <= tq) ? x : -INFINITY;
                    pvv[kf][r] = x;
                    mx = fmaxf(mx, x);
                }
            mx = fmaxf(mx, __shfl_xor(mx, 16));
            mx = fmaxf(mx, __shfl_xor(mx, 32));
            float mnew = fmaxf(m_s, mx);
            float corr = __expf(m_s - mnew);     // 0 on first tile
            m_s = mnew;
            float ps = 0.f;
            #pragma unroll
            for (int kf = 0; kf < 4; ++kf)
                #pragma unroll
                for (int r = 0; r < 4; ++r) {
                    float p = __expf(pvv[kf][r] - mnew);
                    pvv[kf][r] = p;
                    ps += p;
                }
            ps += __shfl_xor(ps, 16);
            ps += __shfl_xor(ps, 32);
            l_s = l_s * corr + ps;

            // P^T -> LDS [q][key], vector writes
            #pragma unroll
            for (int kf = 0; kf < 4; ++kf) {
                float4 w4 = make_float4(pvv[kf][0], pvv[kf][1], pvv[kf][2], pvv[kf][3]);
                *(float4*)&Pl[l16][kf * 16 + g * 4] = w4;
            }

            // rescale O (corr lives on softmax row q=l16; fetch per acc row)
            #pragma unroll
            for (int r = 0; r < 4; ++r) {
                float cr = __shfl(corr, g * 4 + r);
                #pragma unroll
                for (int df = 0; df < 4; ++df)
                    oacc[df][r] *= cr;
            }

            // re-fragment P: A[m=q][k=key]; lane reads Pl[l16][ks*32+g*8..+7]
            bf16x8 ap[2];
            #pragma unroll
            for (int ks = 0; ks < 2; ++ks) {
                const float* pr = &Pl[l16][ks * 32 + g * 8];
                bf16x8 tmp;
                #pragma unroll
                for (int jj = 0; jj < 8; ++jj)
                    tmp[jj] = (short)f2bf(pr[jj]);
                ap[ks] = tmp;
            }

            // Y += P.V
            #pragma unroll
            for (int df = 0; df < 4; ++df)
                #pragma unroll
                for (int ks = 0; ks < 2; ++ks)
                    oacc[df] = __builtin_amdgcn_mfma_f32_16x16x32_bf16(ap[ks], bv[df][ks], oacc[df], 0, 0, 0);
        };

        // K-prefetched tile loop (register double buffer, static names)
        loadK(kA, 0);
        for (int k0 = 0; k0 <= q_hi; k0 += 128) {
            if (k0 + 64 <= q_hi) loadK(kB, k0 + 64);
            tile(kA, k0);
            if (k0 + 64 <= q_hi) {
                if (k0 + 128 <= q_hi) loadK(kA, k0 + 128);
                tile(kB, k0 + 64);
            }
        }

        // epilogue: y (B,T,H,HD) fp32
        #pragma unroll
        for (int r = 0; r < 4; ++r) {
            float lr  = __shfl(l_s, g * 4 + r);
            float inv = 1.0f / lr;
            int tqr = tq0 + g * 4 + r;
            #pragma unroll
            for (int df = 0; df < 4; ++df)
                yws[(((size_t)b * T_ + tqr) * H_ + h) * HD_ + df * 16 + l16] =
                    oacc[df][r] * inv;
        }
    }
}

// ---------------------------------------------------------------------------
// Kernel D: out = einsum('btjd,ij->btid', y, out_fact) -> (B,T,D) fp32
// ---------------------------------------------------------------------------
__global__ __launch_bounds__(256) void head_mix_out(const float* __restrict__ yws,
                                                    const float* __restrict__ of,
                                                    float* __restrict__ out) {
    __shared__ float yl[1024];
    __shared__ float f[256];
    const int row = blockIdx.x;
    const float* yr = yws + (size_t)row * D_;
    const int tid = threadIdx.x;
    #pragma unroll
    for (int i = tid; i < 1024; i += 256) yl[i] = yr[i];
    f[tid] = of[tid];
    __syncthreads();
    for (int o = tid; o < 1024; o += 256) {
        int i = o >> 6, d = o & 63;
        float acc = 0.f;
        #pragma unroll
        for (int j = 0; j < 16; ++j) acc += f[i * 16 + j] * yl[j * 64 + d];
        out[(size_t)row * D_ + o] = acc;
    }
}

// ---------------------------------------------------------------------------
extern "C" void kernel_launch(void* const* d_in, const int* in_sizes, int n_in,
                              void* d_out, int out_size, void* d_ws, size_t ws_size,
                              hipStream_t stream) {
    const float* x_norm   = (const float*)d_in[0];
    const float* xt       = (const float*)d_in[1];
    const float* qk_w     = (const float*)d_in[2];
    const float* qk_b     = (const float*)d_in[3];
    const float* v_fact   = (const float*)d_in[4];
    const float* out_fact = (const float*)d_in[5];
    float* out = (float*)d_out;

    const size_t SZ = (size_t)B_ * H_ * T_ * HD_;        // 4M elements
    __hip_bfloat16* qws = (__hip_bfloat16*)d_ws;         // 8 MB
    __hip_bfloat16* kws = qws + SZ;                      // 8 MB
    __hip_bfloat16* vt  = kws + SZ;                      // 8 MB
    float*          yws = (float*)(vt + SZ);             // 16 MB
    __hip_bfloat16* Xb  = (__hip_bfloat16*)(yws + SZ);   // 8 MB
    __hip_bfloat16* Wb  = Xb + SZ;                       // 4 MB

    cast_bf16<<<dim3(2048), 256, 0, stream>>>(x_norm, Xb, 4 * 1024 * 1024 / 8);
    cast_bf16<<<dim3(1024), 256, 0, stream>>>(qk_w, Wb, 2 * 1024 * 1024 / 8);

    qk_gemm_mfma<<<dim3(2048 / 128, 4096 / 128), 256, 0, stream>>>(Xb, Wb, qk_b, qws, kws);
    head_mix_v<<<dim3(B_ * T_ / 2), 256, 0, stream>>>(xt, v_fact, vt);
    attn_mfma<<<dim3(2048), 64, 0, stream>>>(qws, kws, vt, yws);
    head_mix_out<<<dim3(B_ * T_), 256, 0, stream>>>(yws, out_fact, out);
}